// Round 10
// baseline (236.143 us; speedup 1.0000x reference)
//
#include <hip/hip_runtime.h>
#include <math.h>

#define NDIM 128

typedef __bf16 bf16x8 __attribute__((ext_vector_type(8)));
typedef float  f32x4  __attribute__((ext_vector_type(4)));

// f32 pair -> packed bf16x2 (round-to-nearest-even)
__device__ __forceinline__ unsigned pack_bf16x2(float a, float b) {
    unsigned ua = __float_as_uint(a), ub = __float_as_uint(b);
    ua = (ua + 0x7FFFu + ((ua >> 16) & 1u)) >> 16;
    ub = (ub + 0x7FFFu + ((ub >> 16) & 1u)) >> 16;
    return ua | (ub << 16);
}
__device__ __forceinline__ float bf_lo(unsigned p) { return __uint_as_float(p << 16); }
__device__ __forceinline__ float bf_hi(unsigned p) { return __uint_as_float(p & 0xFFFF0000u); }

// ---------------------------------------------------------------------------
// K0: prep. block 0: W[k][n] f32 -> Wt[n][k] bf16.  block 1: s2[] row dots.
// ---------------------------------------------------------------------------
__global__ __launch_bounds__(256) void k_prep(
    const float* __restrict__ W, const float* __restrict__ W_r,
    const float* __restrict__ a, const float* __restrict__ rel_emb,
    unsigned short* __restrict__ Wt, float* __restrict__ s2)
{
    if (blockIdx.x == 0) {
        for (int i = threadIdx.x; i < NDIM * NDIM; i += 256) {
            int n = i & 127, k = i >> 7;
            float v = W[k * NDIM + n];
            Wt[n * NDIM + k] = (unsigned short)(pack_bf16x2(v, 0.f) & 0xFFFFu);
        }
    } else {
        __shared__ float vsh[NDIM];
        const int t = threadIdx.x;
        if (t < 128) {
            float acc = 0.f;
            for (int c = 0; c < NDIM; ++c)
                acc = fmaf(W_r[t * NDIM + c], a[128 + c], acc);
            vsh[t] = acc;
        }
        __syncthreads();
        if (t < 64) {
            float s = 0.f;
            for (int k = 0; k < NDIM; ++k)
                s = fmaf(rel_emb[t * NDIM + k], vsh[k], s);
            s2[t] = s;
        }
    }
}

// ---------------------------------------------------------------------------
// K1: xt = x @ W via mfma_f32_16x16x32_bf16. 128 rows/block, 4 waves.
//     Single 32KB LDS buffer (W, swizzled; reused for output restage).
// ---------------------------------------------------------------------------
__global__ __launch_bounds__(256) void k_xt(
    const float* __restrict__ x, const unsigned short* __restrict__ Wt,
    const float* __restrict__ a,
    unsigned* __restrict__ xtb,   // N*64 uints (bf16x2)
    float* __restrict__ s1, float* __restrict__ s3,
    int n_nodes)
{
    __shared__ __align__(16) unsigned short WL[NDIM * NDIM]; // 32 KB
    const int tid  = threadIdx.x;
    const int lane = tid & 63;
    const int wave = tid >> 6;
    const int l15  = lane & 15;
    const int l4   = lane >> 4;
    char* wb = (char*)WL;

    for (int i = tid * 8; i < NDIM * NDIM; i += 256 * 8) {
        int nn = i >> 7, k = i & 127;
        uint4 v = *reinterpret_cast<const uint4*>(Wt + i);
        *reinterpret_cast<uint4*>(wb + ((nn * 256 + k * 2) ^ ((nn & 7) << 4))) = v;
    }
    __syncthreads();

    const int rowBase = blockIdx.x * 128;

    f32x4 acc[2][8];
    #pragma unroll
    for (int i = 0; i < 2; ++i)
        #pragma unroll
        for (int j = 0; j < 8; ++j) acc[i][j] = (f32x4){0.f, 0.f, 0.f, 0.f};

    #pragma unroll
    for (int kt = 0; kt < 4; ++kt) {
        const int kb2 = (kt * 32 + l4 * 8) * 2;
        bf16x8 af[2], bf[8];
        #pragma unroll
        for (int rf = 0; rf < 2; ++rf) {
            int r = rowBase + wave * 32 + rf * 16 + l15;
            float4 lo = make_float4(0.f, 0.f, 0.f, 0.f);
            float4 hi = lo;
            if (r < n_nodes) {
                const float* px = &x[(size_t)r * NDIM + kt * 32 + l4 * 8];
                lo = *reinterpret_cast<const float4*>(px);
                hi = *reinterpret_cast<const float4*>(px + 4);
            }
            uint4 u;
            u.x = pack_bf16x2(lo.x, lo.y);
            u.y = pack_bf16x2(lo.z, lo.w);
            u.z = pack_bf16x2(hi.x, hi.y);
            u.w = pack_bf16x2(hi.z, hi.w);
            af[rf] = __builtin_bit_cast(bf16x8, u);
        }
        #pragma unroll
        for (int cf = 0; cf < 8; ++cf) {
            int n = cf * 16 + l15;
            bf[cf] = *reinterpret_cast<bf16x8*>(wb + ((n * 256 + kb2) ^ ((n & 7) << 4)));
        }
        #pragma unroll
        for (int rf = 0; rf < 2; ++rf)
            #pragma unroll
            for (int cf = 0; cf < 8; ++cf)
                acc[rf][cf] = __builtin_amdgcn_mfma_f32_16x16x32_bf16(
                    af[rf], bf[cf], acc[rf][cf], 0, 0, 0);
    }

    // s1/s3: C/D layout col=lane&15, row=(lane>>4)*4+reg
    float av1[8], av3[8];
    #pragma unroll
    for (int cf = 0; cf < 8; ++cf) {
        av1[cf] = a[cf * 16 + l15];
        av3[cf] = a[256 + cf * 16 + l15];
    }
    #pragma unroll
    for (int rf = 0; rf < 2; ++rf) {
        #pragma unroll
        for (int reg = 0; reg < 4; ++reg) {
            float p1 = 0.f, p3 = 0.f;
            #pragma unroll
            for (int cf = 0; cf < 8; ++cf) {
                p1 = fmaf(acc[rf][cf][reg], av1[cf], p1);
                p3 = fmaf(acc[rf][cf][reg], av3[cf], p3);
            }
            #pragma unroll
            for (int off = 8; off; off >>= 1) {
                p1 += __shfl_xor(p1, off);
                p3 += __shfl_xor(p3, off);
            }
            if (l15 == 0) {
                int r = rowBase + wave * 32 + rf * 16 + l4 * 4 + reg;
                if (r < n_nodes) { s1[r] = p1; s3[r] = p3; }
            }
        }
    }

    __syncthreads();
    #pragma unroll
    for (int rf = 0; rf < 2; ++rf)
        #pragma unroll
        for (int cf = 0; cf < 8; ++cf)
            #pragma unroll
            for (int reg = 0; reg < 4; ++reg) {
                int r = wave * 32 + rf * 16 + l4 * 4 + reg;
                int c = cf * 16 + l15;
                *reinterpret_cast<unsigned short*>(wb + ((r * 256 + c * 2) ^ ((r & 7) << 4))) =
                    (unsigned short)(pack_bf16x2(acc[rf][cf][reg], 0.f) & 0xFFFFu);
            }
    __syncthreads();
    for (int i = tid * 8; i < NDIM * NDIM; i += 256 * 8) {
        int r = i >> 7, k = i & 127;
        if (rowBase + r < n_nodes) {
            uint4 v = *reinterpret_cast<uint4*>(wb + ((r * 256 + k * 2) ^ ((r & 7) << 4)));
            *reinterpret_cast<uint4*>(&xtb[(size_t)(rowBase + r) * 64 + (k >> 1)]) = v;
        }
    }
}

// ---------------------------------------------------------------------------
// K3: in-degree histogram only (no ordinal output), 4 edges/thread
// ---------------------------------------------------------------------------
__global__ __launch_bounds__(256) void k_count(
    const int* __restrict__ dst, int* __restrict__ deg, int n_edges)
{
    int e = (blockIdx.x * 256 + threadIdx.x) * 4;
    if (e + 3 < n_edges) {
        int4 d = *reinterpret_cast<const int4*>(&dst[e]);
        atomicAdd(&deg[d.x], 1);
        atomicAdd(&deg[d.y], 1);
        atomicAdd(&deg[d.z], 1);
        atomicAdd(&deg[d.w], 1);
    } else {
        for (int k = 0; k < 4 && e + k < n_edges; ++k)
            atomicAdd(&deg[dst[e + k]], 1);
    }
}

// ---------------------------------------------------------------------------
// K4a: block-local exclusive scan via wave shuffles -> cursor, block totals
// ---------------------------------------------------------------------------
__global__ __launch_bounds__(1024) void k_scan1(
    const int* __restrict__ deg, int* __restrict__ cursor,
    int* __restrict__ btot, int n)
{
    __shared__ int wt[16];
    const int tid = threadIdx.x;
    const int lane = tid & 63;
    const int wv = tid >> 6;
    const int i = blockIdx.x * 1024 + tid;
    int v = (i < n) ? deg[i] : 0;
    int s = v;
    #pragma unroll
    for (int off = 1; off < 64; off <<= 1) {
        int t = __shfl_up(s, off);
        if (lane >= off) s += t;
    }
    if (lane == 63) wt[wv] = s;
    __syncthreads();
    if (wv == 0) {
        int x = (lane < 16) ? wt[lane] : 0;
        #pragma unroll
        for (int off = 1; off < 16; off <<= 1) {
            int t = __shfl_up(x, off);
            if (lane >= off) x += t;
        }
        if (lane < 16) wt[lane] = x;
        if (lane == 15) btot[blockIdx.x] = x;
    }
    __syncthreads();
    int base = (wv == 0) ? 0 : wt[wv - 1];
    if (i < n) cursor[i] = base + s - v;     // exclusive within block
}

// K4b: exclusive scan of block totals (one block; nb <= 128)
__global__ __launch_bounds__(128) void k_scan2(int* __restrict__ bt, int nb)
{
    __shared__ int sh[128];
    const int t = threadIdx.x;
    int v = (t < nb) ? bt[t] : 0;
    sh[t] = v;
    __syncthreads();
    for (int off = 1; off < 128; off <<= 1) {
        int x = sh[t];
        if (t >= off) x += sh[t - off];
        __syncthreads();
        sh[t] = x;
        __syncthreads();
    }
    if (t < nb) bt[t] = sh[t] - v;
}

// K4c: fold block prefix -> cursor becomes absolute row start (4/thread)
__global__ __launch_bounds__(256) void k_fixup(
    int* __restrict__ cursor, const int* __restrict__ bpre, int n)
{
    int i = (blockIdx.x * 256 + threadIdx.x) * 4;
    if (i + 3 < n) {
        int b = bpre[i >> 10];                // 4-aligned: never crosses 1024
        int4 v = *reinterpret_cast<int4*>(&cursor[i]);
        v.x += b; v.y += b; v.z += b; v.w += b;
        *reinterpret_cast<int4*>(&cursor[i]) = v;
    } else {
        for (int k = 0; k < 4 && i + k < n; ++k)
            cursor[i + k] += bpre[(i + k) >> 10];
    }
}

// ---------------------------------------------------------------------------
// K5: CSR placement, 4 edges/thread. pos comes from the atomicAdd itself
//     (cursor = row start, post-place cursor[n] = rowstart[n+1]).
//     rec = 4B {src:17 | et:6}; 2 random ops/edge, zero gathers.
// ---------------------------------------------------------------------------
__global__ __launch_bounds__(256) void k_place(
    const int* __restrict__ src, const int* __restrict__ dst,
    const int* __restrict__ etype,
    int* __restrict__ cursor, unsigned* __restrict__ rec, int n_edges)
{
    int e = (blockIdx.x * 256 + threadIdx.x) * 4;
    if (e + 3 < n_edges) {
        int4 sv = *reinterpret_cast<const int4*>(&src[e]);
        int4 dv = *reinterpret_cast<const int4*>(&dst[e]);
        int4 tv = *reinterpret_cast<const int4*>(&etype[e]);
        int p0 = atomicAdd(&cursor[dv.x], 1);
        int p1 = atomicAdd(&cursor[dv.y], 1);
        int p2 = atomicAdd(&cursor[dv.z], 1);
        int p3 = atomicAdd(&cursor[dv.w], 1);
        atomicExch(&rec[p0], ((unsigned)sv.x << 7) | (unsigned)tv.x);
        atomicExch(&rec[p1], ((unsigned)sv.y << 7) | (unsigned)tv.y);
        atomicExch(&rec[p2], ((unsigned)sv.z << 7) | (unsigned)tv.z);
        atomicExch(&rec[p3], ((unsigned)sv.w << 7) | (unsigned)tv.w);
    } else {
        for (int k = 0; k < 4 && e + k < n_edges; ++k) {
            int pos = atomicAdd(&cursor[dst[e + k]], 1);
            atomicExch(&rec[pos], ((unsigned)src[e + k] << 7) | (unsigned)etype[e + k]);
        }
    }
}

// ---------------------------------------------------------------------------
// K6: gather-reduce + in-place weight computation. One wave per node,
//     4x16-lane quarters, lane owns 8 cols (dwordx4/row), batch-4.
//     start/cnt from final cursor: start=cursor[n-1], end=cursor[n].
//     w = exp(lrelu(s1[src]+s2[et]+s3[n])) computed here (redundant/lane).
// ---------------------------------------------------------------------------
__global__ __launch_bounds__(256) void k_gather(
    const char* __restrict__ xtb, const unsigned* __restrict__ rec,
    const int* __restrict__ cursor,
    const float* __restrict__ s1, const float* __restrict__ s2,
    const float* __restrict__ s3,
    float* __restrict__ out, int n_nodes)
{
    __shared__ float s2l[64];
    if (threadIdx.x < 64) s2l[threadIdx.x] = s2[threadIdx.x];
    __syncthreads();

    const int n = blockIdx.x * 4 + (threadIdx.x >> 6);
    if (n >= n_nodes) return;
    const int lane = threadIdx.x & 63;
    const int l15  = lane & 15;
    const int q    = lane >> 4;
    const int end   = cursor[n];
    const int beg   = (n == 0) ? 0 : cursor[n - 1];
    const int start = __builtin_amdgcn_readfirstlane(beg);
    const int cnt   = __builtin_amdgcn_readfirstlane(end - beg);
    const float s3n = s3[n];
    const int cq    = (cnt + 3) >> 2;            // chunk per quarter
    const int qm    = min(cq, cnt - q * cq);     // valid entries this quarter
    const unsigned laneoff = (unsigned)l15 * 16u;

    float acc[8] = {0.f, 0.f, 0.f, 0.f, 0.f, 0.f, 0.f, 0.f};
    float wsum = 0.f;

    for (int k0 = 0; k0 < cq; k0 += 4) {
        unsigned rr[4];
        #pragma unroll
        for (int j = 0; j < 4; ++j) {
            int li  = q * cq + k0 + j;
            int idx = start + min(li, cnt - 1);  // cnt>=1 whenever loop runs
            rr[j] = __builtin_nontemporal_load(&rec[idx]);
        }
        float s1v[4];
        uint4 p[4];
        #pragma unroll
        for (int j = 0; j < 4; ++j) {
            unsigned sidx = rr[j] >> 7;
            s1v[j] = s1[sidx];
            p[j] = *reinterpret_cast<const uint4*>(xtb + (size_t)((sidx << 8) + laneoff));
        }
        #pragma unroll
        for (int j = 0; j < 4; ++j) {
            float v = s1v[j] + s2l[rr[j] & 63u] + s3n;
            v = (v >= 0.f) ? v : 0.2f * v;
            float w = ((k0 + j) < qm) ? __expf(v) : 0.f;
            wsum += w;
            acc[0] = fmaf(w, bf_lo(p[j].x), acc[0]);
            acc[1] = fmaf(w, bf_hi(p[j].x), acc[1]);
            acc[2] = fmaf(w, bf_lo(p[j].y), acc[2]);
            acc[3] = fmaf(w, bf_hi(p[j].y), acc[3]);
            acc[4] = fmaf(w, bf_lo(p[j].z), acc[4]);
            acc[5] = fmaf(w, bf_hi(p[j].z), acc[5]);
            acc[6] = fmaf(w, bf_lo(p[j].w), acc[6]);
            acc[7] = fmaf(w, bf_hi(p[j].w), acc[7]);
        }
    }

    #pragma unroll
    for (int j = 0; j < 8; ++j) {
        acc[j] += __shfl_xor(acc[j], 16);
        acc[j] += __shfl_xor(acc[j], 32);
    }
    wsum += __shfl_xor(wsum, 16);
    wsum += __shfl_xor(wsum, 32);

    if (q == 0) {
        const float inv = 1.0f / (wsum + 1e-10f);
        f32x4 o0 = {acc[0] * inv, acc[1] * inv, acc[2] * inv, acc[3] * inv};
        f32x4 o1 = {acc[4] * inv, acc[5] * inv, acc[6] * inv, acc[7] * inv};
        f32x4* po = reinterpret_cast<f32x4*>(out + (size_t)n * NDIM + l15 * 8);
        __builtin_nontemporal_store(o0, po);
        __builtin_nontemporal_store(o1, po + 1);
    }
}

extern "C" void kernel_launch(void* const* d_in, const int* in_sizes, int n_in,
                              void* d_out, int out_size, void* d_ws, size_t ws_size,
                              hipStream_t stream)
{
    const float* x    = (const float*)d_in[0];
    const int*   ei   = (const int*)d_in[1];   // [2,E]: src row then dst row
    const int*   et   = (const int*)d_in[2];
    const float* W    = (const float*)d_in[3];
    const float* W_r  = (const float*)d_in[4];
    const float* a    = (const float*)d_in[5];
    const float* rel  = (const float*)d_in[6];
    float* out = (float*)d_out;

    const int E  = in_sizes[2];
    const int N  = in_sizes[0] / NDIM;
    const int NB = (N + 1023) / 1024;           // 98 (<=128 req'd by k_scan2)

    char* p = (char*)d_ws;
    auto take = [&](size_t bytes) {
        char* q = p;
        p += (bytes + 15) & ~(size_t)15;
        return q;
    };
    unsigned* xtb        = (unsigned*)take((size_t)N * 64 * 4);   // bf16x2
    unsigned short* Wt   = (unsigned short*)take(NDIM * NDIM * 2);
    float* s1            = (float*)take((size_t)N * 4);
    float* s3            = (float*)take((size_t)N * 4);
    float* s2            = (float*)take(64 * 4);
    int* deg             = (int*)take((size_t)N * 4);
    int* cursor          = (int*)take((size_t)N * 4);
    int* btot            = (int*)take(128 * 4);
    unsigned* rec        = (unsigned*)take((size_t)E * 4);        // {src:17|et:6}

    const int* srcArr = ei;
    const int* dstArr = ei + E;

    (void)hipMemsetAsync(deg, 0, (size_t)N * sizeof(int), stream);

    k_prep<<<2, 256, 0, stream>>>(W, W_r, a, rel, Wt, s2);
    k_xt<<<(N + 127) / 128, 256, 0, stream>>>(x, Wt, a, xtb, s1, s3, N);
    k_count<<<(E + 1023) / 1024, 256, 0, stream>>>(dstArr, deg, E);
    k_scan1<<<NB, 1024, 0, stream>>>(deg, cursor, btot, N);
    k_scan2<<<1, 128, 0, stream>>>(btot, NB);
    k_fixup<<<(N + 1023) / 1024, 256, 0, stream>>>(cursor, btot, N);
    k_place<<<(E + 1023) / 1024, 256, 0, stream>>>(
        srcArr, dstArr, et, cursor, rec, E);
    k_gather<<<(N + 3) / 4, 256, 0, stream>>>(
        (const char*)xtb, rec, cursor, s1, s2, s3, out, N);
}

// Round 11
// 189.345 us; speedup vs baseline: 1.2472x; 1.2472x over previous
//
#include <hip/hip_runtime.h>
#include <math.h>

#define NDIM 128

typedef __bf16 bf16x8 __attribute__((ext_vector_type(8)));
typedef float  f32x4  __attribute__((ext_vector_type(4)));

// f32 pair -> packed bf16x2 (round-to-nearest-even)
__device__ __forceinline__ unsigned pack_bf16x2(float a, float b) {
    unsigned ua = __float_as_uint(a), ub = __float_as_uint(b);
    ua = (ua + 0x7FFFu + ((ua >> 16) & 1u)) >> 16;
    ub = (ub + 0x7FFFu + ((ub >> 16) & 1u)) >> 16;
    return ua | (ub << 16);
}
__device__ __forceinline__ float bf_lo(unsigned p) { return __uint_as_float(p << 16); }
__device__ __forceinline__ float bf_hi(unsigned p) { return __uint_as_float(p & 0xFFFF0000u); }

// ---------------------------------------------------------------------------
// K0: prep. block 0: W[k][n] f32 -> Wt[n][k] bf16.  block 1: s2[] row dots.
// ---------------------------------------------------------------------------
__global__ __launch_bounds__(256) void k_prep(
    const float* __restrict__ W, const float* __restrict__ W_r,
    const float* __restrict__ a, const float* __restrict__ rel_emb,
    unsigned short* __restrict__ Wt, float* __restrict__ s2)
{
    if (blockIdx.x == 0) {
        for (int i = threadIdx.x; i < NDIM * NDIM; i += 256) {
            int n = i & 127, k = i >> 7;
            float v = W[k * NDIM + n];
            Wt[n * NDIM + k] = (unsigned short)(pack_bf16x2(v, 0.f) & 0xFFFFu);
        }
    } else {
        __shared__ float vsh[NDIM];
        const int t = threadIdx.x;
        if (t < 128) {
            float acc = 0.f;
            for (int c = 0; c < NDIM; ++c)
                acc = fmaf(W_r[t * NDIM + c], a[128 + c], acc);
            vsh[t] = acc;
        }
        __syncthreads();
        if (t < 64) {
            float s = 0.f;
            for (int k = 0; k < NDIM; ++k)
                s = fmaf(rel_emb[t * NDIM + k], vsh[k], s);
            s2[t] = s;
        }
    }
}

// ---------------------------------------------------------------------------
// K1: xt = x @ W via mfma_f32_16x16x32_bf16. 128 rows/block, 4 waves.
//     Single 32KB LDS buffer (W, swizzled; reused for output restage).
// ---------------------------------------------------------------------------
__global__ __launch_bounds__(256) void k_xt(
    const float* __restrict__ x, const unsigned short* __restrict__ Wt,
    const float* __restrict__ a,
    unsigned* __restrict__ xtb,   // N*64 uints (bf16x2)
    float* __restrict__ s1, float* __restrict__ s3,
    int n_nodes)
{
    __shared__ __align__(16) unsigned short WL[NDIM * NDIM]; // 32 KB
    const int tid  = threadIdx.x;
    const int lane = tid & 63;
    const int wave = tid >> 6;
    const int l15  = lane & 15;
    const int l4   = lane >> 4;
    char* wb = (char*)WL;

    for (int i = tid * 8; i < NDIM * NDIM; i += 256 * 8) {
        int nn = i >> 7, k = i & 127;
        uint4 v = *reinterpret_cast<const uint4*>(Wt + i);
        *reinterpret_cast<uint4*>(wb + ((nn * 256 + k * 2) ^ ((nn & 7) << 4))) = v;
    }
    __syncthreads();

    const int rowBase = blockIdx.x * 128;

    f32x4 acc[2][8];
    #pragma unroll
    for (int i = 0; i < 2; ++i)
        #pragma unroll
        for (int j = 0; j < 8; ++j) acc[i][j] = (f32x4){0.f, 0.f, 0.f, 0.f};

    #pragma unroll
    for (int kt = 0; kt < 4; ++kt) {
        const int kb2 = (kt * 32 + l4 * 8) * 2;
        bf16x8 af[2], bf[8];
        #pragma unroll
        for (int rf = 0; rf < 2; ++rf) {
            int r = rowBase + wave * 32 + rf * 16 + l15;
            float4 lo = make_float4(0.f, 0.f, 0.f, 0.f);
            float4 hi = lo;
            if (r < n_nodes) {
                const float* px = &x[(size_t)r * NDIM + kt * 32 + l4 * 8];
                lo = *reinterpret_cast<const float4*>(px);
                hi = *reinterpret_cast<const float4*>(px + 4);
            }
            uint4 u;
            u.x = pack_bf16x2(lo.x, lo.y);
            u.y = pack_bf16x2(lo.z, lo.w);
            u.z = pack_bf16x2(hi.x, hi.y);
            u.w = pack_bf16x2(hi.z, hi.w);
            af[rf] = __builtin_bit_cast(bf16x8, u);
        }
        #pragma unroll
        for (int cf = 0; cf < 8; ++cf) {
            int n = cf * 16 + l15;
            bf[cf] = *reinterpret_cast<bf16x8*>(wb + ((n * 256 + kb2) ^ ((n & 7) << 4)));
        }
        #pragma unroll
        for (int rf = 0; rf < 2; ++rf)
            #pragma unroll
            for (int cf = 0; cf < 8; ++cf)
                acc[rf][cf] = __builtin_amdgcn_mfma_f32_16x16x32_bf16(
                    af[rf], bf[cf], acc[rf][cf], 0, 0, 0);
    }

    // s1/s3: C/D layout col=lane&15, row=(lane>>4)*4+reg
    float av1[8], av3[8];
    #pragma unroll
    for (int cf = 0; cf < 8; ++cf) {
        av1[cf] = a[cf * 16 + l15];
        av3[cf] = a[256 + cf * 16 + l15];
    }
    #pragma unroll
    for (int rf = 0; rf < 2; ++rf) {
        #pragma unroll
        for (int reg = 0; reg < 4; ++reg) {
            float p1 = 0.f, p3 = 0.f;
            #pragma unroll
            for (int cf = 0; cf < 8; ++cf) {
                p1 = fmaf(acc[rf][cf][reg], av1[cf], p1);
                p3 = fmaf(acc[rf][cf][reg], av3[cf], p3);
            }
            #pragma unroll
            for (int off = 8; off; off >>= 1) {
                p1 += __shfl_xor(p1, off);
                p3 += __shfl_xor(p3, off);
            }
            if (l15 == 0) {
                int r = rowBase + wave * 32 + rf * 16 + l4 * 4 + reg;
                if (r < n_nodes) { s1[r] = p1; s3[r] = p3; }
            }
        }
    }

    __syncthreads();
    #pragma unroll
    for (int rf = 0; rf < 2; ++rf)
        #pragma unroll
        for (int cf = 0; cf < 8; ++cf)
            #pragma unroll
            for (int reg = 0; reg < 4; ++reg) {
                int r = wave * 32 + rf * 16 + l4 * 4 + reg;
                int c = cf * 16 + l15;
                *reinterpret_cast<unsigned short*>(wb + ((r * 256 + c * 2) ^ ((r & 7) << 4))) =
                    (unsigned short)(pack_bf16x2(acc[rf][cf][reg], 0.f) & 0xFFFFu);
            }
    __syncthreads();
    for (int i = tid * 8; i < NDIM * NDIM; i += 256 * 8) {
        int r = i >> 7, k = i & 127;
        if (rowBase + r < n_nodes) {
            uint4 v = *reinterpret_cast<uint4*>(wb + ((r * 256 + k * 2) ^ ((r & 7) << 4)));
            *reinterpret_cast<uint4*>(&xtb[(size_t)(rowBase + r) * 64 + (k >> 1)]) = v;
        }
    }
}

// ---------------------------------------------------------------------------
// K3: in-degree histogram, 4 edges/thread; ordinal = returned old count
//     (independent atomics -> pipelined, unlike cursor-chained placement)
// ---------------------------------------------------------------------------
__global__ __launch_bounds__(256) void k_count(
    const int* __restrict__ dst, int* __restrict__ deg,
    int* __restrict__ eord, int n_edges)
{
    int e = (blockIdx.x * 256 + threadIdx.x) * 4;
    if (e + 3 < n_edges) {
        int4 d = *reinterpret_cast<const int4*>(&dst[e]);
        int4 o;
        o.x = atomicAdd(&deg[d.x], 1);
        o.y = atomicAdd(&deg[d.y], 1);
        o.z = atomicAdd(&deg[d.z], 1);
        o.w = atomicAdd(&deg[d.w], 1);
        *reinterpret_cast<int4*>(&eord[e]) = o;
    } else {
        for (int k = 0; k < 4 && e + k < n_edges; ++k)
            eord[e + k] = atomicAdd(&deg[dst[e + k]], 1);
    }
}

// ---------------------------------------------------------------------------
// K4a: block scan via wave shuffles; packed = {block-local prefix:20, deg:12}
// ---------------------------------------------------------------------------
__global__ __launch_bounds__(1024) void k_scan1(
    const int* __restrict__ deg, int* __restrict__ packed,
    int* __restrict__ btot, int n)
{
    __shared__ int wt[16];
    const int tid = threadIdx.x;
    const int lane = tid & 63;
    const int wv = tid >> 6;
    const int i = blockIdx.x * 1024 + tid;
    int v = (i < n) ? deg[i] : 0;
    int s = v;
    #pragma unroll
    for (int off = 1; off < 64; off <<= 1) {
        int t = __shfl_up(s, off);
        if (lane >= off) s += t;
    }
    if (lane == 63) wt[wv] = s;
    __syncthreads();
    if (wv == 0) {
        int x = (lane < 16) ? wt[lane] : 0;
        #pragma unroll
        for (int off = 1; off < 16; off <<= 1) {
            int t = __shfl_up(x, off);
            if (lane >= off) x += t;
        }
        if (lane < 16) wt[lane] = x;
        if (lane == 15) btot[blockIdx.x] = x;
    }
    __syncthreads();
    int base = (wv == 0) ? 0 : wt[wv - 1];
    if (i < n)
        packed[i] = (int)(((unsigned)(base + s - v) << 12) | (unsigned)v);
}

// K4b: exclusive scan of block totals (one block; nb <= 128)
__global__ __launch_bounds__(128) void k_scan2(int* __restrict__ bt, int nb)
{
    __shared__ int sh[128];
    const int t = threadIdx.x;
    int v = (t < nb) ? bt[t] : 0;
    sh[t] = v;
    __syncthreads();
    for (int off = 1; off < 128; off <<= 1) {
        int x = sh[t];
        if (t >= off) x += sh[t - off];
        __syncthreads();
        sh[t] = x;
        __syncthreads();
    }
    if (t < nb) bt[t] = sh[t] - v;
}

// K4c: fold block prefix into packed's prefix field (4/thread, streaming)
__global__ __launch_bounds__(256) void k_fixup(
    int* __restrict__ packed, const int* __restrict__ bpre, int n)
{
    int i = (blockIdx.x * 256 + threadIdx.x) * 4;
    if (i + 3 < n) {
        int b = bpre[i >> 10] << 12;          // 4-aligned: never crosses 1024
        int4 v = *reinterpret_cast<int4*>(&packed[i]);
        v.x += b; v.y += b; v.z += b; v.w += b;
        *reinterpret_cast<int4*>(&packed[i]) = v;
    } else {
        for (int k = 0; k < 4 && i + k < n; ++k)
            packed[i + k] += bpre[(i + k) >> 10] << 12;
    }
}

// ---------------------------------------------------------------------------
// K5: CSR placement only (weights deferred to k_gather). 4 edges/thread.
//     Per edge: ONE random gather (packed[dst]) + one 4B atomicExch
//     (16B writeback granularity vs 64B line for plain scattered stores).
// ---------------------------------------------------------------------------
__global__ __launch_bounds__(256) void k_place(
    const int* __restrict__ src, const int* __restrict__ dst,
    const int* __restrict__ etype, const int* __restrict__ eord,
    const int* __restrict__ packed,
    unsigned* __restrict__ rec, int n_edges)
{
    int e = (blockIdx.x * 256 + threadIdx.x) * 4;
    if (e >= n_edges) return;
    if (e + 3 < n_edges) {
        int4 sv = *reinterpret_cast<const int4*>(&src[e]);
        int4 dv = *reinterpret_cast<const int4*>(&dst[e]);
        int4 tv = *reinterpret_cast<const int4*>(&etype[e]);
        int4 ov = *reinterpret_cast<const int4*>(&eord[e]);
        int da[4] = {dv.x, dv.y, dv.z, dv.w};
        int sa[4] = {sv.x, sv.y, sv.z, sv.w};
        int ta[4] = {tv.x, tv.y, tv.z, tv.w};
        int oa[4] = {ov.x, ov.y, ov.z, ov.w};
        int pk[4];
        #pragma unroll
        for (int j = 0; j < 4; ++j) pk[j] = packed[da[j]];
        #pragma unroll
        for (int j = 0; j < 4; ++j) {
            int pos = (int)(((unsigned)pk[j]) >> 12) + oa[j];
            atomicExch(&rec[pos], ((unsigned)sa[j] << 6) | (unsigned)ta[j]);
        }
    } else {
        for (int k = 0; k < 4 && e + k < n_edges; ++k) {
            int pos = (int)(((unsigned)packed[dst[e + k]]) >> 12) + eord[e + k];
            atomicExch(&rec[pos], ((unsigned)src[e + k] << 6) | (unsigned)etype[e + k]);
        }
    }
}

// ---------------------------------------------------------------------------
// K6: gather-reduce + in-place weight computation (validated in round 10).
//     One wave per node, 4x16-lane quarters, lane owns 8 cols, batch-4.
//     w = exp(lrelu(s1[src]+s2[et]+s3[n])); s1[src] is a broadcast line
//     riding with the row fetch; s2 in LDS; s3[n] uniform per node.
// ---------------------------------------------------------------------------
__global__ __launch_bounds__(256) void k_gather(
    const char* __restrict__ xtb, const unsigned* __restrict__ rec,
    const int* __restrict__ packed,
    const float* __restrict__ s1, const float* __restrict__ s2,
    const float* __restrict__ s3,
    float* __restrict__ out, int n_nodes)
{
    __shared__ float s2l[64];
    if (threadIdx.x < 64) s2l[threadIdx.x] = s2[threadIdx.x];
    __syncthreads();

    const int n = blockIdx.x * 4 + (threadIdx.x >> 6);
    if (n >= n_nodes) return;
    const int lane = threadIdx.x & 63;
    const int l15  = lane & 15;
    const int q    = lane >> 4;
    const unsigned pd = (unsigned)packed[n];
    const int start = __builtin_amdgcn_readfirstlane((int)(pd >> 12));
    const int cnt   = __builtin_amdgcn_readfirstlane((int)(pd & 0xFFFu));
    const float s3n = s3[n];
    const int cq    = (cnt + 3) >> 2;            // chunk per quarter
    const int qm    = min(cq, cnt - q * cq);     // valid entries this quarter
    const unsigned laneoff = (unsigned)l15 * 16u;

    float acc[8] = {0.f, 0.f, 0.f, 0.f, 0.f, 0.f, 0.f, 0.f};
    float wsum = 0.f;

    for (int k0 = 0; k0 < cq; k0 += 4) {
        unsigned rr[4];
        #pragma unroll
        for (int j = 0; j < 4; ++j) {
            int li  = q * cq + k0 + j;
            int idx = start + min(li, cnt - 1);  // cnt>=1 whenever loop runs
            rr[j] = __builtin_nontemporal_load(&rec[idx]);
        }
        float s1v[4];
        uint4 p[4];
        #pragma unroll
        for (int j = 0; j < 4; ++j) {
            unsigned sidx = rr[j] >> 6;
            s1v[j] = s1[sidx];
            p[j] = *reinterpret_cast<const uint4*>(xtb + (size_t)((sidx << 8) + laneoff));
        }
        #pragma unroll
        for (int j = 0; j < 4; ++j) {
            float v = s1v[j] + s2l[rr[j] & 63u] + s3n;
            v = (v >= 0.f) ? v : 0.2f * v;
            float w = ((k0 + j) < qm) ? __expf(v) : 0.f;
            wsum += w;
            acc[0] = fmaf(w, bf_lo(p[j].x), acc[0]);
            acc[1] = fmaf(w, bf_hi(p[j].x), acc[1]);
            acc[2] = fmaf(w, bf_lo(p[j].y), acc[2]);
            acc[3] = fmaf(w, bf_hi(p[j].y), acc[3]);
            acc[4] = fmaf(w, bf_lo(p[j].z), acc[4]);
            acc[5] = fmaf(w, bf_hi(p[j].z), acc[5]);
            acc[6] = fmaf(w, bf_lo(p[j].w), acc[6]);
            acc[7] = fmaf(w, bf_hi(p[j].w), acc[7]);
        }
    }

    #pragma unroll
    for (int j = 0; j < 8; ++j) {
        acc[j] += __shfl_xor(acc[j], 16);
        acc[j] += __shfl_xor(acc[j], 32);
    }
    wsum += __shfl_xor(wsum, 16);
    wsum += __shfl_xor(wsum, 32);

    if (q == 0) {
        const float inv = 1.0f / (wsum + 1e-10f);
        f32x4 o0 = {acc[0] * inv, acc[1] * inv, acc[2] * inv, acc[3] * inv};
        f32x4 o1 = {acc[4] * inv, acc[5] * inv, acc[6] * inv, acc[7] * inv};
        f32x4* po = reinterpret_cast<f32x4*>(out + (size_t)n * NDIM + l15 * 8);
        __builtin_nontemporal_store(o0, po);
        __builtin_nontemporal_store(o1, po + 1);
    }
}

extern "C" void kernel_launch(void* const* d_in, const int* in_sizes, int n_in,
                              void* d_out, int out_size, void* d_ws, size_t ws_size,
                              hipStream_t stream)
{
    const float* x    = (const float*)d_in[0];
    const int*   ei   = (const int*)d_in[1];   // [2,E]: src row then dst row
    const int*   et   = (const int*)d_in[2];
    const float* W    = (const float*)d_in[3];
    const float* W_r  = (const float*)d_in[4];
    const float* a    = (const float*)d_in[5];
    const float* rel  = (const float*)d_in[6];
    float* out = (float*)d_out;

    const int E  = in_sizes[2];
    const int N  = in_sizes[0] / NDIM;
    const int NB = (N + 1023) / 1024;           // 98 (<=128 req'd by k_scan2)

    char* p = (char*)d_ws;
    auto take = [&](size_t bytes) {
        char* q = p;
        p += (bytes + 15) & ~(size_t)15;
        return q;
    };
    unsigned* xtb        = (unsigned*)take((size_t)N * 64 * 4);   // bf16x2
    unsigned short* Wt   = (unsigned short*)take(NDIM * NDIM * 2);
    float* s1            = (float*)take((size_t)N * 4);
    float* s3            = (float*)take((size_t)N * 4);
    float* s2            = (float*)take(64 * 4);
    int* deg             = (int*)take((size_t)N * 4);
    int* packed          = (int*)take((size_t)N * 4);   // {prefix:20|deg:12}
    int* btot            = (int*)take(128 * 4);
    int* eord            = (int*)take((size_t)E * 4);
    unsigned* rec        = (unsigned*)take((size_t)E * 4);        // {src:17|et:6}

    const int* srcArr = ei;
    const int* dstArr = ei + E;

    (void)hipMemsetAsync(deg, 0, (size_t)N * sizeof(int), stream);

    k_prep<<<2, 256, 0, stream>>>(W, W_r, a, rel, Wt, s2);
    k_xt<<<(N + 127) / 128, 256, 0, stream>>>(x, Wt, a, xtb, s1, s3, N);
    k_count<<<(E + 1023) / 1024, 256, 0, stream>>>(dstArr, deg, eord, E);
    k_scan1<<<NB, 1024, 0, stream>>>(deg, packed, btot, N);
    k_scan2<<<1, 128, 0, stream>>>(btot, NB);
    k_fixup<<<(N + 1023) / 1024, 256, 0, stream>>>(packed, btot, N);
    k_place<<<(E + 1023) / 1024, 256, 0, stream>>>(
        srcArr, dstArr, et, eord, packed, rec, E);
    k_gather<<<(N + 3) / 4, 256, 0, stream>>>(
        (const char*)xtb, rec, packed, s1, s2, s3, out, N);
}

// Round 12
// 172.614 us; speedup vs baseline: 1.3680x; 1.0969x over previous
//
#include <hip/hip_runtime.h>
#include <math.h>

#define NDIM 128

typedef __bf16 bf16x8 __attribute__((ext_vector_type(8)));
typedef float  f32x4  __attribute__((ext_vector_type(4)));

// f32 pair -> packed bf16x2 (round-to-nearest-even)
__device__ __forceinline__ unsigned pack_bf16x2(float a, float b) {
    unsigned ua = __float_as_uint(a), ub = __float_as_uint(b);
    ua = (ua + 0x7FFFu + ((ua >> 16) & 1u)) >> 16;
    ub = (ub + 0x7FFFu + ((ub >> 16) & 1u)) >> 16;
    return ua | (ub << 16);
}
__device__ __forceinline__ float bf_lo(unsigned p) { return __uint_as_float(p << 16); }
__device__ __forceinline__ float bf_hi(unsigned p) { return __uint_as_float(p & 0xFFFF0000u); }

// ---------------------------------------------------------------------------
// D1: blocks 0-1 = prep (W transpose->bf16, s2 row dots);
//     blocks 2+  = in-degree histogram (4 edges/thread, eord = old count)
// ---------------------------------------------------------------------------
__global__ __launch_bounds__(256) void k_prep_count(
    const float* __restrict__ W, const float* __restrict__ W_r,
    const float* __restrict__ a, const float* __restrict__ rel_emb,
    unsigned short* __restrict__ Wt, float* __restrict__ s2,
    const int* __restrict__ dst, int* __restrict__ deg,
    int* __restrict__ eord, int n_edges)
{
    if (blockIdx.x == 0) {
        for (int i = threadIdx.x; i < NDIM * NDIM; i += 256) {
            int n = i & 127, k = i >> 7;
            float v = W[k * NDIM + n];
            Wt[n * NDIM + k] = (unsigned short)(pack_bf16x2(v, 0.f) & 0xFFFFu);
        }
        return;
    }
    if (blockIdx.x == 1) {
        __shared__ float vsh[NDIM];
        const int t = threadIdx.x;
        if (t < 128) {
            float acc = 0.f;
            for (int c = 0; c < NDIM; ++c)
                acc = fmaf(W_r[t * NDIM + c], a[128 + c], acc);
            vsh[t] = acc;
        }
        __syncthreads();
        if (t < 64) {
            float s = 0.f;
            for (int k = 0; k < NDIM; ++k)
                s = fmaf(rel_emb[t * NDIM + k], vsh[k], s);
            s2[t] = s;
        }
        return;
    }
    int e = ((blockIdx.x - 2) * 256 + threadIdx.x) * 4;
    if (e + 3 < n_edges) {
        int4 d = *reinterpret_cast<const int4*>(&dst[e]);
        int4 o;
        o.x = atomicAdd(&deg[d.x], 1);
        o.y = atomicAdd(&deg[d.y], 1);
        o.z = atomicAdd(&deg[d.z], 1);
        o.w = atomicAdd(&deg[d.w], 1);
        *reinterpret_cast<int4*>(&eord[e]) = o;
    } else {
        for (int k = 0; k < 4 && e + k < n_edges; ++k)
            eord[e + k] = atomicAdd(&deg[dst[e + k]], 1);
    }
}

// ---------------------------------------------------------------------------
// D2: block scan, 256 threads x 4 elems. packed = {block-local prefix:20,deg:12}
// ---------------------------------------------------------------------------
__global__ __launch_bounds__(256) void k_scan1(
    const int* __restrict__ deg, int* __restrict__ packed,
    int* __restrict__ btot, int n)
{
    __shared__ int wt[4];
    const int tid = threadIdx.x, lane = tid & 63, wv = tid >> 6;
    const int i0 = blockIdx.x * 1024 + tid * 4;
    int d0 = 0, d1 = 0, d2 = 0, d3 = 0;
    if (i0 + 3 < n) {
        int4 v = *reinterpret_cast<const int4*>(&deg[i0]);
        d0 = v.x; d1 = v.y; d2 = v.z; d3 = v.w;
    } else {
        if (i0     < n) d0 = deg[i0];
        if (i0 + 1 < n) d1 = deg[i0 + 1];
        if (i0 + 2 < n) d2 = deg[i0 + 2];
    }
    const int sum = d0 + d1 + d2 + d3;
    int s = sum;
    #pragma unroll
    for (int off = 1; off < 64; off <<= 1) {
        int t = __shfl_up(s, off);
        if (lane >= off) s += t;
    }
    if (lane == 63) wt[wv] = s;
    __syncthreads();
    int base = 0;
    #pragma unroll
    for (int w = 0; w < 3; ++w)
        if (w < wv) base += wt[w];
    if (tid == 255) btot[blockIdx.x] = base + s;
    int p = base + s - sum;                       // exclusive prefix of this group
    if (i0 + 3 < n) {
        int4 o;
        o.x = (p << 12) | d0;              p += d0;
        o.y = (p << 12) | d1;              p += d1;
        o.z = (p << 12) | d2;              p += d2;
        o.w = (p << 12) | d3;
        *reinterpret_cast<int4*>(&packed[i0]) = o;
    } else {
        if (i0     < n) { packed[i0]     = (p << 12) | d0; p += d0; }
        if (i0 + 1 < n) { packed[i0 + 1] = (p << 12) | d1; p += d1; }
        if (i0 + 2 < n) { packed[i0 + 2] = (p << 12) | d2; }
    }
}

// ---------------------------------------------------------------------------
// D3: fixup — each block reduces btot[0..bid-1] itself (wave 0), then folds
//     the block prefix into its 1024 packed entries. (k_scan2 eliminated)
// ---------------------------------------------------------------------------
__global__ __launch_bounds__(256) void k_fixup(
    int* __restrict__ packed, const int* __restrict__ btot, int n)
{
    __shared__ int bsh;
    const int tid = threadIdx.x;
    const int bid = blockIdx.x;
    if (tid < 64) {
        int acc = 0;
        if (tid < bid)      acc  = btot[tid];
        if (64 + tid < bid) acc += btot[64 + tid];
        #pragma unroll
        for (int off = 32; off; off >>= 1) acc += __shfl_xor(acc, off);
        if (tid == 0) bsh = acc;
    }
    __syncthreads();
    const int badd = bsh << 12;
    int i = bid * 1024 + tid * 4;
    if (i + 3 < n) {
        int4 v = *reinterpret_cast<int4*>(&packed[i]);
        v.x += badd; v.y += badd; v.z += badd; v.w += badd;
        *reinterpret_cast<int4*>(&packed[i]) = v;
    } else {
        for (int k = 0; k < 4 && i + k < n; ++k) packed[i + k] += badd;
    }
}

// ---------------------------------------------------------------------------
// D4: blocks [0, nxtb)  = xt GEMM (mfma 16x16x32 bf16, 128 rows/block);
//     blocks [nxtb, ..) = CSR placement (1 gather + 1 4B atomicExch per edge).
//     Independent workloads co-resident in one dispatch (BW-heavy || latency-
//     heavy) — place needs no s1/s3 since weights are fused into k_gather.
// ---------------------------------------------------------------------------
__global__ __launch_bounds__(256) void k_xt_place(
    const float* __restrict__ x, const unsigned short* __restrict__ Wt,
    const float* __restrict__ a,
    unsigned* __restrict__ xtb, float* __restrict__ s1, float* __restrict__ s3,
    int n_nodes, int nxtb,
    const int* __restrict__ src, const int* __restrict__ dst,
    const int* __restrict__ etype, const int* __restrict__ eord,
    const int* __restrict__ packed, unsigned* __restrict__ rec, int n_edges)
{
    if ((int)blockIdx.x >= nxtb) {
        // ----- place branch -----
        int e = (((int)blockIdx.x - nxtb) * 256 + threadIdx.x) * 4;
        if (e >= n_edges) return;
        if (e + 3 < n_edges) {
            int4 sv = *reinterpret_cast<const int4*>(&src[e]);
            int4 dv = *reinterpret_cast<const int4*>(&dst[e]);
            int4 tv = *reinterpret_cast<const int4*>(&etype[e]);
            int4 ov = *reinterpret_cast<const int4*>(&eord[e]);
            int da[4] = {dv.x, dv.y, dv.z, dv.w};
            int sa[4] = {sv.x, sv.y, sv.z, sv.w};
            int ta[4] = {tv.x, tv.y, tv.z, tv.w};
            int oa[4] = {ov.x, ov.y, ov.z, ov.w};
            int pk[4];
            #pragma unroll
            for (int j = 0; j < 4; ++j) pk[j] = packed[da[j]];
            #pragma unroll
            for (int j = 0; j < 4; ++j) {
                int pos = (int)(((unsigned)pk[j]) >> 12) + oa[j];
                atomicExch(&rec[pos], ((unsigned)sa[j] << 6) | (unsigned)ta[j]);
            }
        } else {
            for (int k = 0; k < 4 && e + k < n_edges; ++k) {
                int pos = (int)(((unsigned)packed[dst[e + k]]) >> 12) + eord[e + k];
                atomicExch(&rec[pos], ((unsigned)src[e + k] << 6) | (unsigned)etype[e + k]);
            }
        }
        return;
    }

    // ----- xt branch -----
    __shared__ __align__(16) unsigned short WL[NDIM * NDIM]; // 32 KB
    const int tid  = threadIdx.x;
    const int lane = tid & 63;
    const int wave = tid >> 6;
    const int l15  = lane & 15;
    const int l4   = lane >> 4;
    char* wb = (char*)WL;

    for (int i = tid * 8; i < NDIM * NDIM; i += 256 * 8) {
        int nn = i >> 7, k = i & 127;
        uint4 v = *reinterpret_cast<const uint4*>(Wt + i);
        *reinterpret_cast<uint4*>(wb + ((nn * 256 + k * 2) ^ ((nn & 7) << 4))) = v;
    }
    __syncthreads();

    const int rowBase = blockIdx.x * 128;

    f32x4 acc[2][8];
    #pragma unroll
    for (int i = 0; i < 2; ++i)
        #pragma unroll
        for (int j = 0; j < 8; ++j) acc[i][j] = (f32x4){0.f, 0.f, 0.f, 0.f};

    #pragma unroll
    for (int kt = 0; kt < 4; ++kt) {
        const int kb2 = (kt * 32 + l4 * 8) * 2;
        bf16x8 af[2], bf[8];
        #pragma unroll
        for (int rf = 0; rf < 2; ++rf) {
            int r = rowBase + wave * 32 + rf * 16 + l15;
            float4 lo = make_float4(0.f, 0.f, 0.f, 0.f);
            float4 hi = lo;
            if (r < n_nodes) {
                const float* px = &x[(size_t)r * NDIM + kt * 32 + l4 * 8];
                lo = *reinterpret_cast<const float4*>(px);
                hi = *reinterpret_cast<const float4*>(px + 4);
            }
            uint4 u;
            u.x = pack_bf16x2(lo.x, lo.y);
            u.y = pack_bf16x2(lo.z, lo.w);
            u.z = pack_bf16x2(hi.x, hi.y);
            u.w = pack_bf16x2(hi.z, hi.w);
            af[rf] = __builtin_bit_cast(bf16x8, u);
        }
        #pragma unroll
        for (int cf = 0; cf < 8; ++cf) {
            int n = cf * 16 + l15;
            bf[cf] = *reinterpret_cast<bf16x8*>(wb + ((n * 256 + kb2) ^ ((n & 7) << 4)));
        }
        #pragma unroll
        for (int rf = 0; rf < 2; ++rf)
            #pragma unroll
            for (int cf = 0; cf < 8; ++cf)
                acc[rf][cf] = __builtin_amdgcn_mfma_f32_16x16x32_bf16(
                    af[rf], bf[cf], acc[rf][cf], 0, 0, 0);
    }

    // s1/s3: C/D layout col=lane&15, row=(lane>>4)*4+reg
    float av1[8], av3[8];
    #pragma unroll
    for (int cf = 0; cf < 8; ++cf) {
        av1[cf] = a[cf * 16 + l15];
        av3[cf] = a[256 + cf * 16 + l15];
    }
    #pragma unroll
    for (int rf = 0; rf < 2; ++rf) {
        #pragma unroll
        for (int reg = 0; reg < 4; ++reg) {
            float p1 = 0.f, p3 = 0.f;
            #pragma unroll
            for (int cf = 0; cf < 8; ++cf) {
                p1 = fmaf(acc[rf][cf][reg], av1[cf], p1);
                p3 = fmaf(acc[rf][cf][reg], av3[cf], p3);
            }
            #pragma unroll
            for (int off = 8; off; off >>= 1) {
                p1 += __shfl_xor(p1, off);
                p3 += __shfl_xor(p3, off);
            }
            if (l15 == 0) {
                int r = rowBase + wave * 32 + rf * 16 + l4 * 4 + reg;
                if (r < n_nodes) { s1[r] = p1; s3[r] = p3; }
            }
        }
    }

    __syncthreads();
    #pragma unroll
    for (int rf = 0; rf < 2; ++rf)
        #pragma unroll
        for (int cf = 0; cf < 8; ++cf)
            #pragma unroll
            for (int reg = 0; reg < 4; ++reg) {
                int r = wave * 32 + rf * 16 + l4 * 4 + reg;
                int c = cf * 16 + l15;
                *reinterpret_cast<unsigned short*>(wb + ((r * 256 + c * 2) ^ ((r & 7) << 4))) =
                    (unsigned short)(pack_bf16x2(acc[rf][cf][reg], 0.f) & 0xFFFFu);
            }
    __syncthreads();
    for (int i = tid * 8; i < NDIM * NDIM; i += 256 * 8) {
        int r = i >> 7, k = i & 127;
        if (rowBase + r < n_nodes) {
            uint4 v = *reinterpret_cast<uint4*>(wb + ((r * 256 + k * 2) ^ ((r & 7) << 4)));
            *reinterpret_cast<uint4*>(&xtb[(size_t)(rowBase + r) * 64 + (k >> 1)]) = v;
        }
    }
}

// ---------------------------------------------------------------------------
// D5: gather-reduce + fused weights. One wave per node, 4x16-lane quarters,
//     lane owns 8 cols, batch-4. Weight computed by ONE lane group per edge
//     (lane l15&3 handles edge je), broadcast via __shfl — kills the 16x
//     redundant s1-load + exp per quarter (round-11 VALUBusy was 56%).
// ---------------------------------------------------------------------------
__global__ __launch_bounds__(256) void k_gather(
    const char* __restrict__ xtb, const unsigned* __restrict__ rec,
    const int* __restrict__ packed,
    const float* __restrict__ s1, const float* __restrict__ s2,
    const float* __restrict__ s3,
    float* __restrict__ out, int n_nodes)
{
    __shared__ float s2l[64];
    if (threadIdx.x < 64) s2l[threadIdx.x] = s2[threadIdx.x];
    __syncthreads();

    const int n = blockIdx.x * 4 + (threadIdx.x >> 6);
    if (n >= n_nodes) return;
    const int lane = threadIdx.x & 63;
    const int l15  = lane & 15;
    const int q    = lane >> 4;
    const unsigned pd = (unsigned)packed[n];
    const int start = __builtin_amdgcn_readfirstlane((int)(pd >> 12));
    const int cnt   = __builtin_amdgcn_readfirstlane((int)(pd & 0xFFFu));
    const float s3n = s3[n];
    const int cq    = (cnt + 3) >> 2;            // chunk per quarter
    const int qm    = min(cq, cnt - q * cq);     // valid entries this quarter
    const unsigned laneoff = (unsigned)l15 * 16u;
    const int lbase = lane & 48;                 // q*16

    float acc[8] = {0.f, 0.f, 0.f, 0.f, 0.f, 0.f, 0.f, 0.f};
    float wsum = 0.f;

    for (int k0 = 0; k0 < cq; k0 += 4) {
        const int li0 = q * cq + k0;
        unsigned rr0 = __builtin_nontemporal_load(&rec[start + min(li0,     cnt - 1)]);
        unsigned rr1 = __builtin_nontemporal_load(&rec[start + min(li0 + 1, cnt - 1)]);
        unsigned rr2 = __builtin_nontemporal_load(&rec[start + min(li0 + 2, cnt - 1)]);
        unsigned rr3 = __builtin_nontemporal_load(&rec[start + min(li0 + 3, cnt - 1)]);

        // lane-split weight: lane with je==j computes w for edge k0+j
        const int je = l15 & 3;
        unsigned rrj = (je == 0) ? rr0 : (je == 1) ? rr1 : (je == 2) ? rr2 : rr3;
        float vv = s1[rrj >> 6] + s2l[rrj & 63u] + s3n;
        vv = (vv >= 0.f) ? vv : 0.2f * vv;
        float wm = ((k0 + je) < qm) ? __expf(vv) : 0.f;
        float w0 = __shfl(wm, lbase + 0);
        float w1 = __shfl(wm, lbase + 1);
        float w2 = __shfl(wm, lbase + 2);
        float w3 = __shfl(wm, lbase + 3);

        uint4 p0 = *reinterpret_cast<const uint4*>(xtb + (size_t)(((rr0 >> 6) << 8) + laneoff));
        uint4 p1 = *reinterpret_cast<const uint4*>(xtb + (size_t)(((rr1 >> 6) << 8) + laneoff));
        uint4 p2 = *reinterpret_cast<const uint4*>(xtb + (size_t)(((rr2 >> 6) << 8) + laneoff));
        uint4 p3 = *reinterpret_cast<const uint4*>(xtb + (size_t)(((rr3 >> 6) << 8) + laneoff));

        wsum += w0 + w1 + w2 + w3;
        acc[0] = fmaf(w0, bf_lo(p0.x), acc[0]); acc[1] = fmaf(w0, bf_hi(p0.x), acc[1]);
        acc[2] = fmaf(w0, bf_lo(p0.y), acc[2]); acc[3] = fmaf(w0, bf_hi(p0.y), acc[3]);
        acc[4] = fmaf(w0, bf_lo(p0.z), acc[4]); acc[5] = fmaf(w0, bf_hi(p0.z), acc[5]);
        acc[6] = fmaf(w0, bf_lo(p0.w), acc[6]); acc[7] = fmaf(w0, bf_hi(p0.w), acc[7]);
        acc[0] = fmaf(w1, bf_lo(p1.x), acc[0]); acc[1] = fmaf(w1, bf_hi(p1.x), acc[1]);
        acc[2] = fmaf(w1, bf_lo(p1.y), acc[2]); acc[3] = fmaf(w1, bf_hi(p1.y), acc[3]);
        acc[4] = fmaf(w1, bf_lo(p1.z), acc[4]); acc[5] = fmaf(w1, bf_hi(p1.z), acc[5]);
        acc[6] = fmaf(w1, bf_lo(p1.w), acc[6]); acc[7] = fmaf(w1, bf_hi(p1.w), acc[7]);
        acc[0] = fmaf(w2, bf_lo(p2.x), acc[0]); acc[1] = fmaf(w2, bf_hi(p2.x), acc[1]);
        acc[2] = fmaf(w2, bf_lo(p2.y), acc[2]); acc[3] = fmaf(w2, bf_hi(p2.y), acc[3]);
        acc[4] = fmaf(w2, bf_lo(p2.z), acc[4]); acc[5] = fmaf(w2, bf_hi(p2.z), acc[5]);
        acc[6] = fmaf(w2, bf_lo(p2.w), acc[6]); acc[7] = fmaf(w2, bf_hi(p2.w), acc[7]);
        acc[0] = fmaf(w3, bf_lo(p3.x), acc[0]); acc[1] = fmaf(w3, bf_hi(p3.x), acc[1]);
        acc[2] = fmaf(w3, bf_lo(p3.y), acc[2]); acc[3] = fmaf(w3, bf_hi(p3.y), acc[3]);
        acc[4] = fmaf(w3, bf_lo(p3.z), acc[4]); acc[5] = fmaf(w3, bf_hi(p3.z), acc[5]);
        acc[6] = fmaf(w3, bf_lo(p3.w), acc[6]); acc[7] = fmaf(w3, bf_hi(p3.w), acc[7]);
    }

    #pragma unroll
    for (int j = 0; j < 8; ++j) {
        acc[j] += __shfl_xor(acc[j], 16);
        acc[j] += __shfl_xor(acc[j], 32);
    }
    wsum += __shfl_xor(wsum, 16);
    wsum += __shfl_xor(wsum, 32);

    if (q == 0) {
        const float inv = 1.0f / (wsum + 1e-10f);
        f32x4 o0 = {acc[0] * inv, acc[1] * inv, acc[2] * inv, acc[3] * inv};
        f32x4 o1 = {acc[4] * inv, acc[5] * inv, acc[6] * inv, acc[7] * inv};
        f32x4* po = reinterpret_cast<f32x4*>(out + (size_t)n * NDIM + l15 * 8);
        __builtin_nontemporal_store(o0, po);
        __builtin_nontemporal_store(o1, po + 1);
    }
}

extern "C" void kernel_launch(void* const* d_in, const int* in_sizes, int n_in,
                              void* d_out, int out_size, void* d_ws, size_t ws_size,
                              hipStream_t stream)
{
    const float* x    = (const float*)d_in[0];
    const int*   ei   = (const int*)d_in[1];   // [2,E]: src row then dst row
    const int*   et   = (const int*)d_in[2];
    const float* W    = (const float*)d_in[3];
    const float* W_r  = (const float*)d_in[4];
    const float* a    = (const float*)d_in[5];
    const float* rel  = (const float*)d_in[6];
    float* out = (float*)d_out;

    const int E    = in_sizes[2];
    const int N    = in_sizes[0] / NDIM;
    const int NB   = (N + 1023) / 1024;        // 98 scan/fixup blocks
    const int NXT  = (N + 127) / 128;          // 782 xt blocks
    const int NPL  = (E + 1023) / 1024;        // 977 place/count blocks

    char* p = (char*)d_ws;
    auto take = [&](size_t bytes) {
        char* q = p;
        p += (bytes + 15) & ~(size_t)15;
        return q;
    };
    unsigned* xtb        = (unsigned*)take((size_t)N * 64 * 4);   // bf16x2
    unsigned short* Wt   = (unsigned short*)take(NDIM * NDIM * 2);
    float* s1            = (float*)take((size_t)N * 4);
    float* s3            = (float*)take((size_t)N * 4);
    float* s2            = (float*)take(64 * 4);
    int* deg             = (int*)take((size_t)N * 4);
    int* packed          = (int*)take((size_t)N * 4);   // {prefix:20|deg:12}
    int* btot            = (int*)take(128 * 4);
    int* eord            = (int*)take((size_t)E * 4);
    unsigned* rec        = (unsigned*)take((size_t)E * 4);        // {src:17|et:6}

    const int* srcArr = ei;
    const int* dstArr = ei + E;

    (void)hipMemsetAsync(deg, 0, (size_t)N * sizeof(int), stream);

    k_prep_count<<<2 + NPL, 256, 0, stream>>>(
        W, W_r, a, rel, Wt, s2, dstArr, deg, eord, E);
    k_scan1<<<NB, 256, 0, stream>>>(deg, packed, btot, N);
    k_fixup<<<NB, 256, 0, stream>>>(packed, btot, N);
    k_xt_place<<<NXT + NPL, 256, 0, stream>>>(
        x, Wt, a, xtb, s1, s3, N, NXT,
        srcArr, dstArr, et, eord, packed, rec, E);
    k_gather<<<(N + 3) / 4, 256, 0, stream>>>(
        (const char*)xtb, rec, packed, s1, s2, s3, out, N);
}

// Round 13
// 168.567 us; speedup vs baseline: 1.4009x; 1.0240x over previous
//
#include <hip/hip_runtime.h>
#include <math.h>

#define NDIM 128

typedef __bf16 bf16x8 __attribute__((ext_vector_type(8)));
typedef float  f32x4  __attribute__((ext_vector_type(4)));

// f32 pair -> packed bf16x2 (round-to-nearest-even)
__device__ __forceinline__ unsigned pack_bf16x2(float a, float b) {
    unsigned ua = __float_as_uint(a), ub = __float_as_uint(b);
    ua = (ua + 0x7FFFu + ((ua >> 16) & 1u)) >> 16;
    ub = (ub + 0x7FFFu + ((ub >> 16) & 1u)) >> 16;
    return ua | (ub << 16);
}
__device__ __forceinline__ float bf_lo(unsigned p) { return __uint_as_float(p << 16); }
__device__ __forceinline__ float bf_hi(unsigned p) { return __uint_as_float(p & 0xFFFF0000u); }

// ---------------------------------------------------------------------------
// D1: blocks 0-1 = prep (W transpose->bf16, s2 row dots);
//     blocks 2+  = in-degree histogram (4 edges/thread, eord = old count)
// ---------------------------------------------------------------------------
__global__ __launch_bounds__(256) void k_prep_count(
    const float* __restrict__ W, const float* __restrict__ W_r,
    const float* __restrict__ a, const float* __restrict__ rel_emb,
    unsigned short* __restrict__ Wt, float* __restrict__ s2,
    const int* __restrict__ dst, int* __restrict__ deg,
    int* __restrict__ eord, int n_edges)
{
    if (blockIdx.x == 0) {
        for (int i = threadIdx.x; i < NDIM * NDIM; i += 256) {
            int n = i & 127, k = i >> 7;
            float v = W[k * NDIM + n];
            Wt[n * NDIM + k] = (unsigned short)(pack_bf16x2(v, 0.f) & 0xFFFFu);
        }
        return;
    }
    if (blockIdx.x == 1) {
        __shared__ float vsh[NDIM];
        const int t = threadIdx.x;
        if (t < 128) {
            float acc = 0.f;
            for (int c = 0; c < NDIM; ++c)
                acc = fmaf(W_r[t * NDIM + c], a[128 + c], acc);
            vsh[t] = acc;
        }
        __syncthreads();
        if (t < 64) {
            float s = 0.f;
            for (int k = 0; k < NDIM; ++k)
                s = fmaf(rel_emb[t * NDIM + k], vsh[k], s);
            s2[t] = s;
        }
        return;
    }
    int e = ((blockIdx.x - 2) * 256 + threadIdx.x) * 4;
    if (e + 3 < n_edges) {
        int4 d = *reinterpret_cast<const int4*>(&dst[e]);
        int4 o;
        o.x = atomicAdd(&deg[d.x], 1);
        o.y = atomicAdd(&deg[d.y], 1);
        o.z = atomicAdd(&deg[d.z], 1);
        o.w = atomicAdd(&deg[d.w], 1);
        *reinterpret_cast<int4*>(&eord[e]) = o;
    } else {
        for (int k = 0; k < 4 && e + k < n_edges; ++k)
            eord[e + k] = atomicAdd(&deg[dst[e + k]], 1);
    }
}

// ---------------------------------------------------------------------------
// D2: block scan, 256 threads x 4 elems. packed = {block-local prefix:20,deg:12}
// ---------------------------------------------------------------------------
__global__ __launch_bounds__(256) void k_scan1(
    const int* __restrict__ deg, int* __restrict__ packed,
    int* __restrict__ btot, int n)
{
    __shared__ int wt[4];
    const int tid = threadIdx.x, lane = tid & 63, wv = tid >> 6;
    const int i0 = blockIdx.x * 1024 + tid * 4;
    int d0 = 0, d1 = 0, d2 = 0, d3 = 0;
    if (i0 + 3 < n) {
        int4 v = *reinterpret_cast<const int4*>(&deg[i0]);
        d0 = v.x; d1 = v.y; d2 = v.z; d3 = v.w;
    } else {
        if (i0     < n) d0 = deg[i0];
        if (i0 + 1 < n) d1 = deg[i0 + 1];
        if (i0 + 2 < n) d2 = deg[i0 + 2];
    }
    const int sum = d0 + d1 + d2 + d3;
    int s = sum;
    #pragma unroll
    for (int off = 1; off < 64; off <<= 1) {
        int t = __shfl_up(s, off);
        if (lane >= off) s += t;
    }
    if (lane == 63) wt[wv] = s;
    __syncthreads();
    int base = 0;
    #pragma unroll
    for (int w = 0; w < 3; ++w)
        if (w < wv) base += wt[w];
    if (tid == 255) btot[blockIdx.x] = base + s;
    int p = base + s - sum;                       // exclusive prefix of this group
    if (i0 + 3 < n) {
        int4 o;
        o.x = (p << 12) | d0;              p += d0;
        o.y = (p << 12) | d1;              p += d1;
        o.z = (p << 12) | d2;              p += d2;
        o.w = (p << 12) | d3;
        *reinterpret_cast<int4*>(&packed[i0]) = o;
    } else {
        if (i0     < n) { packed[i0]     = (p << 12) | d0; p += d0; }
        if (i0 + 1 < n) { packed[i0 + 1] = (p << 12) | d1; p += d1; }
        if (i0 + 2 < n) { packed[i0 + 2] = (p << 12) | d2; }
    }
}

// ---------------------------------------------------------------------------
// D3: fixup — each block reduces btot[0..bid-1] itself (wave 0), then folds
//     the block prefix into its 1024 packed entries.
// ---------------------------------------------------------------------------
__global__ __launch_bounds__(256) void k_fixup(
    int* __restrict__ packed, const int* __restrict__ btot, int n)
{
    __shared__ int bsh;
    const int tid = threadIdx.x;
    const int bid = blockIdx.x;
    if (tid < 64) {
        int acc = 0;
        if (tid < bid)      acc  = btot[tid];
        if (64 + tid < bid) acc += btot[64 + tid];
        #pragma unroll
        for (int off = 32; off; off >>= 1) acc += __shfl_xor(acc, off);
        if (tid == 0) bsh = acc;
    }
    __syncthreads();
    const int badd = bsh << 12;
    int i = bid * 1024 + tid * 4;
    if (i + 3 < n) {
        int4 v = *reinterpret_cast<int4*>(&packed[i]);
        v.x += badd; v.y += badd; v.z += badd; v.w += badd;
        *reinterpret_cast<int4*>(&packed[i]) = v;
    } else {
        for (int k = 0; k < 4 && i + k < n; ++k) packed[i + k] += badd;
    }
}

// ---------------------------------------------------------------------------
// D4: blocks [0, nxtb)  = xt GEMM (mfma 16x16x32 bf16, 128 rows/block);
//     blocks [nxtb, ..) = CSR placement (1 gather + 1 4B atomicExch per edge).
// ---------------------------------------------------------------------------
__global__ __launch_bounds__(256) void k_xt_place(
    const float* __restrict__ x, const unsigned short* __restrict__ Wt,
    const float* __restrict__ a,
    unsigned* __restrict__ xtb, float* __restrict__ s1, float* __restrict__ s3,
    int n_nodes, int nxtb,
    const int* __restrict__ src, const int* __restrict__ dst,
    const int* __restrict__ etype, const int* __restrict__ eord,
    const int* __restrict__ packed, unsigned* __restrict__ rec, int n_edges)
{
    if ((int)blockIdx.x >= nxtb) {
        // ----- place branch -----
        int e = (((int)blockIdx.x - nxtb) * 256 + threadIdx.x) * 4;
        if (e >= n_edges) return;
        if (e + 3 < n_edges) {
            int4 sv = *reinterpret_cast<const int4*>(&src[e]);
            int4 dv = *reinterpret_cast<const int4*>(&dst[e]);
            int4 tv = *reinterpret_cast<const int4*>(&etype[e]);
            int4 ov = *reinterpret_cast<const int4*>(&eord[e]);
            int da[4] = {dv.x, dv.y, dv.z, dv.w};
            int sa[4] = {sv.x, sv.y, sv.z, sv.w};
            int ta[4] = {tv.x, tv.y, tv.z, tv.w};
            int oa[4] = {ov.x, ov.y, ov.z, ov.w};
            int pk[4];
            #pragma unroll
            for (int j = 0; j < 4; ++j) pk[j] = packed[da[j]];
            #pragma unroll
            for (int j = 0; j < 4; ++j) {
                int pos = (int)(((unsigned)pk[j]) >> 12) + oa[j];
                atomicExch(&rec[pos], ((unsigned)sa[j] << 6) | (unsigned)ta[j]);
            }
        } else {
            for (int k = 0; k < 4 && e + k < n_edges; ++k) {
                int pos = (int)(((unsigned)packed[dst[e + k]]) >> 12) + eord[e + k];
                atomicExch(&rec[pos], ((unsigned)src[e + k] << 6) | (unsigned)etype[e + k]);
            }
        }
        return;
    }

    // ----- xt branch -----
    __shared__ __align__(16) unsigned short WL[NDIM * NDIM]; // 32 KB
    const int tid  = threadIdx.x;
    const int lane = tid & 63;
    const int wave = tid >> 6;
    const int l15  = lane & 15;
    const int l4   = lane >> 4;
    char* wb = (char*)WL;

    for (int i = tid * 8; i < NDIM * NDIM; i += 256 * 8) {
        int nn = i >> 7, k = i & 127;
        uint4 v = *reinterpret_cast<const uint4*>(Wt + i);
        *reinterpret_cast<uint4*>(wb + ((nn * 256 + k * 2) ^ ((nn & 7) << 4))) = v;
    }
    __syncthreads();

    const int rowBase = blockIdx.x * 128;

    f32x4 acc[2][8];
    #pragma unroll
    for (int i = 0; i < 2; ++i)
        #pragma unroll
        for (int j = 0; j < 8; ++j) acc[i][j] = (f32x4){0.f, 0.f, 0.f, 0.f};

    #pragma unroll
    for (int kt = 0; kt < 4; ++kt) {
        const int kb2 = (kt * 32 + l4 * 8) * 2;
        bf16x8 af[2], bf[8];
        #pragma unroll
        for (int rf = 0; rf < 2; ++rf) {
            int r = rowBase + wave * 32 + rf * 16 + l15;
            float4 lo = make_float4(0.f, 0.f, 0.f, 0.f);
            float4 hi = lo;
            if (r < n_nodes) {
                const float* px = &x[(size_t)r * NDIM + kt * 32 + l4 * 8];
                lo = *reinterpret_cast<const float4*>(px);
                hi = *reinterpret_cast<const float4*>(px + 4);
            }
            uint4 u;
            u.x = pack_bf16x2(lo.x, lo.y);
            u.y = pack_bf16x2(lo.z, lo.w);
            u.z = pack_bf16x2(hi.x, hi.y);
            u.w = pack_bf16x2(hi.z, hi.w);
            af[rf] = __builtin_bit_cast(bf16x8, u);
        }
        #pragma unroll
        for (int cf = 0; cf < 8; ++cf) {
            int n = cf * 16 + l15;
            bf[cf] = *reinterpret_cast<bf16x8*>(wb + ((n * 256 + kb2) ^ ((n & 7) << 4)));
        }
        #pragma unroll
        for (int rf = 0; rf < 2; ++rf)
            #pragma unroll
            for (int cf = 0; cf < 8; ++cf)
                acc[rf][cf] = __builtin_amdgcn_mfma_f32_16x16x32_bf16(
                    af[rf], bf[cf], acc[rf][cf], 0, 0, 0);
    }

    // s1/s3: C/D layout col=lane&15, row=(lane>>4)*4+reg
    float av1[8], av3[8];
    #pragma unroll
    for (int cf = 0; cf < 8; ++cf) {
        av1[cf] = a[cf * 16 + l15];
        av3[cf] = a[256 + cf * 16 + l15];
    }
    #pragma unroll
    for (int rf = 0; rf < 2; ++rf) {
        #pragma unroll
        for (int reg = 0; reg < 4; ++reg) {
            float p1 = 0.f, p3 = 0.f;
            #pragma unroll
            for (int cf = 0; cf < 8; ++cf) {
                p1 = fmaf(acc[rf][cf][reg], av1[cf], p1);
                p3 = fmaf(acc[rf][cf][reg], av3[cf], p3);
            }
            #pragma unroll
            for (int off = 8; off; off >>= 1) {
                p1 += __shfl_xor(p1, off);
                p3 += __shfl_xor(p3, off);
            }
            if (l15 == 0) {
                int r = rowBase + wave * 32 + rf * 16 + l4 * 4 + reg;
                if (r < n_nodes) { s1[r] = p1; s3[r] = p3; }
            }
        }
    }

    __syncthreads();
    #pragma unroll
    for (int rf = 0; rf < 2; ++rf)
        #pragma unroll
        for (int cf = 0; cf < 8; ++cf)
            #pragma unroll
            for (int reg = 0; reg < 4; ++reg) {
                int r = wave * 32 + rf * 16 + l4 * 4 + reg;
                int c = cf * 16 + l15;
                *reinterpret_cast<unsigned short*>(wb + ((r * 256 + c * 2) ^ ((r & 7) << 4))) =
                    (unsigned short)(pack_bf16x2(acc[rf][cf][reg], 0.f) & 0xFFFFu);
            }
    __syncthreads();
    for (int i = tid * 8; i < NDIM * NDIM; i += 256 * 8) {
        int r = i >> 7, k = i & 127;
        if (rowBase + r < n_nodes) {
            uint4 v = *reinterpret_cast<uint4*>(wb + ((r * 256 + k * 2) ^ ((r & 7) << 4)));
            *reinterpret_cast<uint4*>(&xtb[(size_t)(rowBase + r) * 64 + (k >> 1)]) = v;
        }
    }
}

// ---------------------------------------------------------------------------
// D5: gather-reduce, two-phase weights.
//     Phase 1: lane l owns edge l — one coalesced rec read, one s1 gather,
//              ONE exp per edge. wsum by wave reduce.
//     Phase 2: quarters gather rows; weights AND src indices come from
//              registers via __shfl — zero weight-related memory in loop.
//     (k0+j)<qm guard zeroes cross-quarter duplicates.
// ---------------------------------------------------------------------------
__global__ __launch_bounds__(256) void k_gather(
    const char* __restrict__ xtb, const unsigned* __restrict__ rec,
    const int* __restrict__ packed,
    const float* __restrict__ s1, const float* __restrict__ s2,
    const float* __restrict__ s3,
    float* __restrict__ out, int n_nodes)
{
    __shared__ float s2l[64];
    if (threadIdx.x < 64) s2l[threadIdx.x] = s2[threadIdx.x];
    __syncthreads();

    const int n = blockIdx.x * 4 + (threadIdx.x >> 6);
    if (n >= n_nodes) return;
    const int lane = threadIdx.x & 63;
    const int l15  = lane & 15;
    const int q    = lane >> 4;
    const unsigned pd = (unsigned)packed[n];
    const int start = __builtin_amdgcn_readfirstlane((int)(pd >> 12));
    const int cnt   = __builtin_amdgcn_readfirstlane((int)(pd & 0xFFFu));
    const float s3n = s3[n];

    // ---- phase 1: per-lane weight for edge 'lane' ----
    const int cl = min(cnt, 64);
    unsigned rv = 0u;
    float    wv = 0.f;
    if (lane < cl) {
        rv = __builtin_nontemporal_load(&rec[start + lane]);
        float vv = s1[rv >> 6] + s2l[rv & 63u] + s3n;
        vv = (vv >= 0.f) ? vv : 0.2f * vv;
        wv = __expf(vv);
    }
    float wsum = wv;
    #pragma unroll
    for (int off = 1; off < 64; off <<= 1) wsum += __shfl_xor(wsum, off);

    // ---- phase 2: row gathers; weights/indices via shuffles ----
    const int cq = (cl + 3) >> 2;                 // chunk per quarter
    const int qm = min(cq, cl - q * cq);          // valid entries this quarter
    const unsigned laneoff = (unsigned)l15 * 16u;
    float acc[8] = {0.f, 0.f, 0.f, 0.f, 0.f, 0.f, 0.f, 0.f};

    for (int k0 = 0; k0 < cq; k0 += 4) {
        const int li0 = q * cq + k0;              // <= 63 always
        unsigned rr0 = (unsigned)__shfl((int)rv, li0);
        unsigned rr1 = (unsigned)__shfl((int)rv, li0 + 1);
        unsigned rr2 = (unsigned)__shfl((int)rv, li0 + 2);
        unsigned rr3 = (unsigned)__shfl((int)rv, li0 + 3);
        float w0 = (k0     < qm) ? __shfl(wv, li0)     : 0.f;
        float w1 = (k0 + 1 < qm) ? __shfl(wv, li0 + 1) : 0.f;
        float w2 = (k0 + 2 < qm) ? __shfl(wv, li0 + 2) : 0.f;
        float w3 = (k0 + 3 < qm) ? __shfl(wv, li0 + 3) : 0.f;

        uint4 p0 = *reinterpret_cast<const uint4*>(xtb + (size_t)(((rr0 >> 6) << 8) + laneoff));
        uint4 p1 = *reinterpret_cast<const uint4*>(xtb + (size_t)(((rr1 >> 6) << 8) + laneoff));
        uint4 p2 = *reinterpret_cast<const uint4*>(xtb + (size_t)(((rr2 >> 6) << 8) + laneoff));
        uint4 p3 = *reinterpret_cast<const uint4*>(xtb + (size_t)(((rr3 >> 6) << 8) + laneoff));

        acc[0] = fmaf(w0, bf_lo(p0.x), acc[0]); acc[1] = fmaf(w0, bf_hi(p0.x), acc[1]);
        acc[2] = fmaf(w0, bf_lo(p0.y), acc[2]); acc[3] = fmaf(w0, bf_hi(p0.y), acc[3]);
        acc[4] = fmaf(w0, bf_lo(p0.z), acc[4]); acc[5] = fmaf(w0, bf_hi(p0.z), acc[5]);
        acc[6] = fmaf(w0, bf_lo(p0.w), acc[6]); acc[7] = fmaf(w0, bf_hi(p0.w), acc[7]);
        acc[0] = fmaf(w1, bf_lo(p1.x), acc[0]); acc[1] = fmaf(w1, bf_hi(p1.x), acc[1]);
        acc[2] = fmaf(w1, bf_lo(p1.y), acc[2]); acc[3] = fmaf(w1, bf_hi(p1.y), acc[3]);
        acc[4] = fmaf(w1, bf_lo(p1.z), acc[4]); acc[5] = fmaf(w1, bf_hi(p1.z), acc[5]);
        acc[6] = fmaf(w1, bf_lo(p1.w), acc[6]); acc[7] = fmaf(w1, bf_hi(p1.w), acc[7]);
        acc[0] = fmaf(w2, bf_lo(p2.x), acc[0]); acc[1] = fmaf(w2, bf_hi(p2.x), acc[1]);
        acc[2] = fmaf(w2, bf_lo(p2.y), acc[2]); acc[3] = fmaf(w2, bf_hi(p2.y), acc[3]);
        acc[4] = fmaf(w2, bf_lo(p2.z), acc[4]); acc[5] = fmaf(w2, bf_hi(p2.z), acc[5]);
        acc[6] = fmaf(w2, bf_lo(p2.w), acc[6]); acc[7] = fmaf(w2, bf_hi(p2.w), acc[7]);
        acc[0] = fmaf(w3, bf_lo(p3.x), acc[0]); acc[1] = fmaf(w3, bf_hi(p3.x), acc[1]);
        acc[2] = fmaf(w3, bf_lo(p3.y), acc[2]); acc[3] = fmaf(w3, bf_hi(p3.y), acc[3]);
        acc[4] = fmaf(w3, bf_lo(p3.z), acc[4]); acc[5] = fmaf(w3, bf_hi(p3.z), acc[5]);
        acc[6] = fmaf(w3, bf_lo(p3.w), acc[6]); acc[7] = fmaf(w3, bf_hi(p3.w), acc[7]);
    }

    // ---- rare tail: cnt > 64 (max in-degree here ~35; kept for safety) ----
    if (cnt > 64) {
        float wtail = 0.f;
        for (int li = 64 + q; li < cnt; li += 4) {
            unsigned rr = rec[start + li];
            float vv = s1[rr >> 6] + s2l[rr & 63u] + s3n;
            vv = (vv >= 0.f) ? vv : 0.2f * vv;
            float w = __expf(vv);
            if (l15 == 0) wtail += w;
            uint4 p = *reinterpret_cast<const uint4*>(xtb + (size_t)(((rr >> 6) << 8) + laneoff));
            acc[0] = fmaf(w, bf_lo(p.x), acc[0]); acc[1] = fmaf(w, bf_hi(p.x), acc[1]);
            acc[2] = fmaf(w, bf_lo(p.y), acc[2]); acc[3] = fmaf(w, bf_hi(p.y), acc[3]);
            acc[4] = fmaf(w, bf_lo(p.z), acc[4]); acc[5] = fmaf(w, bf_hi(p.z), acc[5]);
            acc[6] = fmaf(w, bf_lo(p.w), acc[6]); acc[7] = fmaf(w, bf_hi(p.w), acc[7]);
        }
        #pragma unroll
        for (int off = 1; off < 64; off <<= 1) wtail += __shfl_xor(wtail, off);
        wsum += wtail;
    }

    #pragma unroll
    for (int j = 0; j < 8; ++j) {
        acc[j] += __shfl_xor(acc[j], 16);
        acc[j] += __shfl_xor(acc[j], 32);
    }

    if (q == 0) {
        const float inv = 1.0f / (wsum + 1e-10f);
        f32x4 o0 = {acc[0] * inv, acc[1] * inv, acc[2] * inv, acc[3] * inv};
        f32x4 o1 = {acc[4] * inv, acc[5] * inv, acc[6] * inv, acc[7] * inv};
        f32x4* po = reinterpret_cast<f32x4*>(out + (size_t)n * NDIM + l15 * 8);
        __builtin_nontemporal_store(o0, po);
        __builtin_nontemporal_store(o1, po + 1);
    }
}

extern "C" void kernel_launch(void* const* d_in, const int* in_sizes, int n_in,
                              void* d_out, int out_size, void* d_ws, size_t ws_size,
                              hipStream_t stream)
{
    const float* x    = (const float*)d_in[0];
    const int*   ei   = (const int*)d_in[1];   // [2,E]: src row then dst row
    const int*   et   = (const int*)d_in[2];
    const float* W    = (const float*)d_in[3];
    const float* W_r  = (const float*)d_in[4];
    const float* a    = (const float*)d_in[5];
    const float* rel  = (const float*)d_in[6];
    float* out = (float*)d_out;

    const int E    = in_sizes[2];
    const int N    = in_sizes[0] / NDIM;
    const int NB   = (N + 1023) / 1024;        // 98 scan/fixup blocks
    const int NXT  = (N + 127) / 128;          // 782 xt blocks
    const int NPL  = (E + 1023) / 1024;        // 977 place/count blocks

    char* p = (char*)d_ws;
    auto take = [&](size_t bytes) {
        char* q = p;
        p += (bytes + 15) & ~(size_t)15;
        return q;
    };
    unsigned* xtb        = (unsigned*)take((size_t)N * 64 * 4);   // bf16x2
    unsigned short* Wt   = (unsigned short*)take(NDIM * NDIM * 2);
    float* s1            = (float*)take((size_t)N * 4);
    float* s3            = (float*)take((size_t)N * 4);
    float* s2            = (float*)take(64 * 4);
    int* deg             = (int*)take((size_t)N * 4);
    int* packed          = (int*)take((size_t)N * 4);   // {prefix:20|deg:12}
    int* btot            = (int*)take(128 * 4);
    int* eord            = (int*)take((size_t)E * 4);
    unsigned* rec        = (unsigned*)take((size_t)E * 4);        // {src:17|et:6}

    const int* srcArr = ei;
    const int* dstArr = ei + E;

    (void)hipMemsetAsync(deg, 0, (size_t)N * sizeof(int), stream);

    k_prep_count<<<2 + NPL, 256, 0, stream>>>(
        W, W_r, a, rel, Wt, s2, dstArr, deg, eord, E);
    k_scan1<<<NB, 256, 0, stream>>>(deg, packed, btot, N);
    k_fixup<<<NB, 256, 0, stream>>>(packed, btot, N);
    k_xt_place<<<NXT + NPL, 256, 0, stream>>>(
        x, Wt, a, xtb, s1, s3, N, NXT,
        srcArr, dstArr, et, eord, packed, rec, E);
    k_gather<<<(N + 3) / 4, 256, 0, stream>>>(
        (const char*)xtb, rec, packed, s1, s2, s3, out, N);
}